// Round 1
// baseline (9659.781 us; speedup 1.0000x reference)
//
#include <hip/hip_runtime.h>
#include <cstdint>
#include <cstddef>

#define T_ 512
#define B_ 64
#define I_ 512
#define H_ 512

typedef __attribute__((ext_vector_type(8))) short short8;
typedef __attribute__((ext_vector_type(4))) float f32x4;

#define MFMA(a, b, c) __builtin_amdgcn_mfma_f32_16x16x32_bf16((a), (b), (c), 0, 0, 0)

__device__ __forceinline__ unsigned short f2bf(float f) {
  union { float f; unsigned u; } v; v.f = f;
  unsigned r = v.u + 0x7fffu + ((v.u >> 16) & 1u);
  return (unsigned short)(r >> 16);
}

__device__ __forceinline__ float sigm(float x) { return 1.0f / (1.0f + __expf(-x)); }
__device__ __forceinline__ float tanh_fast(float x) {
  float e = __expf(2.0f * x);
  return 1.0f - 2.0f / (e + 1.0f);
}

__device__ __forceinline__ short8 loadWfrag(const float* __restrict__ p) {
  float4 a = ((const float4*)p)[0];
  float4 b = ((const float4*)p)[1];
  short8 r;
  r[0] = (short)f2bf(a.x); r[1] = (short)f2bf(a.y);
  r[2] = (short)f2bf(a.z); r[3] = (short)f2bf(a.w);
  r[4] = (short)f2bf(b.x); r[5] = (short)f2bf(b.y);
  r[6] = (short)f2bf(b.z); r[7] = (short)f2bf(b.w);
  return r;
}

// ---- prep: convert X (T,B,I) fp32 -> bf16 in ws. 16384x256 threads, 1 float4 each.
__global__ void prep_x(const float4* __restrict__ x, ushort4* __restrict__ xb) {
  int i = blockIdx.x * 256 + threadIdx.x;
  float4 v = x[i];
  ushort4 o;
  o.x = f2bf(v.x); o.y = f2bf(v.y); o.z = f2bf(v.z); o.w = f2bf(v.w);
  xb[i] = o;
}

// ---- prep: h0 -> bf16 parity-0 buffers, zero flags. 256x256 threads.
__global__ void prep_init(const float* __restrict__ h0f, const float* __restrict__ h0b,
                          unsigned short* __restrict__ hbufs, int* __restrict__ flags) {
  int i = blockIdx.x * 256 + threadIdx.x;
  if (i < 32768) {
    hbufs[i] = f2bf(h0f[i]);                    // dir0, parity0
  } else {
    int j = i - 32768;
    hbufs[2 * 32768 + j] = f2bf(h0b[j]);        // dir1, parity0
  }
  if (i < 128) flags[i] = 0;
}

// ---- persistent bidirectional LSTM. grid=128 (64 WGs/dir), block=256.
// Barrier-free dataflow: zero LDS, zero __syncthreads. Each wave runs the
// recurrence independently:
//   prefetched-x MFMAs -> poll 64 per-slice wave-counters -> sc1 h loads
//   direct into A-fragments -> h MFMAs -> shfl_xor(8) gate exchange ->
//   epilogue -> sc1 h stores -> s_waitcnt vmcnt(0) -> atomicAdd counter.
// Counter protocol (4 posts/WG/step): consumer at step s waits cnt[i] >= 4*s
// for all 64 producers. Safety of the 2-buffer parity: a wave posts only
// after its own h^s reads completed (they feed its MFMAs, which precede the
// drain), so any wave passing the step-(s+1) poll proves ALL reads of h^s
// are done before h^(s+2) overwrites that buffer.
__global__ __launch_bounds__(256, 1) void lstm_coop(
    const unsigned short* __restrict__ xbf,
    unsigned short* __restrict__ hbufs,
    int* __restrict__ flags,
    const float* __restrict__ Wih_f, const float* __restrict__ Whh_f,
    const float* __restrict__ bih_f, const float* __restrict__ bhh_f,
    const float* __restrict__ c0_f,
    const float* __restrict__ Wih_b, const float* __restrict__ Whh_b,
    const float* __restrict__ bih_b, const float* __restrict__ bhh_b,
    const float* __restrict__ c0_b,
    float* __restrict__ out) {
  const int tid = threadIdx.x;
  const int wave = tid >> 6;
  const int lane = tid & 63;
  const int quad = lane >> 4;
  const int lm = lane & 15;

  const int wg = blockIdx.x;
  const int dir = wg >> 6;       // 0 = forward, 1 = backward
  const int jw = wg & 63;        // hidden-slice index
  const int hb = jw * 8;         // first hidden unit owned

  const float* Wih = dir ? Wih_b : Wih_f;
  const float* Whh = dir ? Whh_b : Whh_f;
  const float* bih = dir ? bih_b : bih_f;
  const float* bhh = dir ? bhh_b : bhh_f;
  const float* c0  = dir ? c0_b  : c0_f;

  // ---- weight fragments: 32 gate rows x K=512, both matrices, in registers ----
  short8 wx[2][16], wh[2][16];
#pragma unroll
  for (int nt = 0; nt < 2; ++nt) {
    int nl = nt * 16 + lm;                         // local gate-row 0..31
    int row = (nl >> 3) * 512 + hb + (nl & 7);     // global row in (4H, 512)
#pragma unroll
    for (int kk = 0; kk < 16; ++kk) {
      int k = kk * 32 + quad * 8;
      wx[nt][kk] = loadWfrag(Wih + (size_t)row * 512 + k);
      wh[nt][kk] = loadWfrag(Whh + (size_t)row * 512 + k);
    }
  }

  // ---- epilogue ownership: lane (quad,lm) -> unit u=lm&7, batches b0..b0+3.
  // Lanes lm and lm+8 duplicate the c/h computation (deterministic identical);
  // only lm<8 stores.
  const int u = lm & 7;
  float bsum[4];
#pragma unroll
  for (int g = 0; g < 4; ++g)
    bsum[g] = bih[g * 512 + hb + u] + bhh[g * 512 + hb + u];

  const int b0 = wave * 16 + quad * 4;
  float creg[4], hlast[4];
#pragma unroll
  for (int r = 0; r < 4; ++r) {
    creg[r] = c0[(size_t)(b0 + r) * 512 + hb + u];
    hlast[r] = 0.f;
  }

  unsigned short* hbuf = hbufs + (size_t)(dir * 2) * 32768;  // parity buffers, my dir
  int* myflags = flags + dir * 64;

  const int arow = wave * 16 + lm;                // batch row this lane feeds to MFMA A
  const unsigned short* xrow = xbf + (size_t)arow * 512 + quad * 8;

  short8 xf[16];                                  // x A-fragments (prefetched)
#define LOADX(tt)                                                         \
  {                                                                       \
    const short8* xs = (const short8*)(xrow + (size_t)(tt) * 32768);      \
    _Pragma("unroll")                                                     \
    for (int kk = 0; kk < 16; ++kk) xf[kk] = xs[kk * 4];                  \
  }

  LOADX(dir ? 511 : 0);

  for (int s = 0; s < 512; ++s) {
    const int t = dir ? (511 - s) : s;

    // ---- wait for h^(s): lane i spins on producer i's wave-counter ----
    {
      const int tgt = 4 * s;
      while (__hip_atomic_load(&myflags[lane], __ATOMIC_RELAXED,
                               __HIP_MEMORY_SCOPE_AGENT) < tgt)
        __builtin_amdgcn_s_sleep(1);
    }
    asm volatile("" ::: "memory");  // compiler fence: keep h loads below the poll

    // ---- issue h A-fragment loads (sc1: bypass stale L2), direct to regs ----
    const unsigned long long* hsrc =
        (const unsigned long long*)(hbuf + (size_t)(s & 1) * 32768) +
        (size_t)arow * 128 + quad * 2;
    unsigned long long hq[32];
#pragma unroll
    for (int kk = 0; kk < 16; ++kk) {
      hq[2 * kk]     = __hip_atomic_load(hsrc + kk * 8,     __ATOMIC_RELAXED, __HIP_MEMORY_SCOPE_AGENT);
      hq[2 * kk + 1] = __hip_atomic_load(hsrc + kk * 8 + 1, __ATOMIC_RELAXED, __HIP_MEMORY_SCOPE_AGENT);
    }

    // ---- x MFMAs (xf prefetched last iter; overlaps h-load latency) ----
    f32x4 acc0 = {0.f, 0.f, 0.f, 0.f};
    f32x4 acc1 = {0.f, 0.f, 0.f, 0.f};
#pragma unroll
    for (int kk = 0; kk < 16; ++kk) {
      acc0 = MFMA(xf[kk], wx[0][kk], acc0);
      acc1 = MFMA(xf[kk], wx[1][kk], acc1);
    }

    // ---- h MFMAs (in-order vmcnt waits against hq) ----
#pragma unroll
    for (int kk = 0; kk < 16; ++kk) {
      ulonglong2 t2; t2.x = hq[2 * kk]; t2.y = hq[2 * kk + 1];
      short8 a = __builtin_bit_cast(short8, t2);
      acc0 = MFMA(a, wh[0][kk], acc0);
      acc1 = MFMA(a, wh[1][kk], acc1);
    }

    // ---- gate exchange within lane pair (lm ^ 8): D col=lane&15 holds
    // i/f (acc0) and g/o (acc1); partner lane has the other half ----
    float hv[4];
#pragma unroll
    for (int r = 0; r < 4; ++r) {
      float p0 = __shfl_xor(acc0[r], 8, 64);
      float p1 = __shfl_xor(acc1[r], 8, 64);
      float gi  = (lm < 8 ? acc0[r] : p0) + bsum[0];
      float gfr = (lm < 8 ? p0 : acc0[r]) + bsum[1];
      float gg  = (lm < 8 ? acc1[r] : p1) + bsum[2];
      float go  = (lm < 8 ? p1 : acc1[r]) + bsum[3];
      float cn = sigm(gfr) * creg[r] + sigm(gi) * tanh_fast(gg);
      creg[r] = cn;
      hv[r] = sigm(go) * tanh_fast(cn);
      hlast[r] = hv[r];
    }
    // unit-pair packing for 4B stores: partner lane (lm^1) has unit u^1
    float q0 = __shfl_xor(hv[0], 1, 64), q1 = __shfl_xor(hv[1], 1, 64);
    float q2 = __shfl_xor(hv[2], 1, 64), q3 = __shfl_xor(hv[3], 1, 64);

    // ---- prefetch x for next step (completes under the sc1 store drain) ----
    {
      int sn = s + 1 < 512 ? s + 1 : 511;
      LOADX(dir ? (511 - sn) : sn);
    }

    // ---- h slice stores (sc1 write-through), 2 x 4B per low lane ----
    unsigned short* hdst = hbuf + (size_t)((s + 1) & 1) * 32768;
    if (lm < 8) {
      unsigned short* hp = hdst + hb + (lm & ~1);
      if ((lm & 1) == 0) {
        unsigned pa = (unsigned)f2bf(hv[0]) | ((unsigned)f2bf(q0) << 16);
        unsigned pb = (unsigned)f2bf(hv[1]) | ((unsigned)f2bf(q1) << 16);
        __hip_atomic_store((unsigned*)(hp + (size_t)(b0 + 0) * 512), pa,
                           __ATOMIC_RELAXED, __HIP_MEMORY_SCOPE_AGENT);
        __hip_atomic_store((unsigned*)(hp + (size_t)(b0 + 1) * 512), pb,
                           __ATOMIC_RELAXED, __HIP_MEMORY_SCOPE_AGENT);
      } else {
        unsigned pa = (unsigned)f2bf(q2) | ((unsigned)f2bf(hv[2]) << 16);
        unsigned pb = (unsigned)f2bf(q3) | ((unsigned)f2bf(hv[3]) << 16);
        __hip_atomic_store((unsigned*)(hp + (size_t)(b0 + 2) * 512), pa,
                           __ATOMIC_RELAXED, __HIP_MEMORY_SCOPE_AGENT);
        __hip_atomic_store((unsigned*)(hp + (size_t)(b0 + 3) * 512), pb,
                           __ATOMIC_RELAXED, __HIP_MEMORY_SCOPE_AGENT);
      }
    }
    // wave-wide drain: all my sc1 h stores at the coherent point, then post
    asm volatile("s_waitcnt vmcnt(0)" ::: "memory");
    if (lane == 0)
      __hip_atomic_fetch_add(&myflags[jw], 1, __ATOMIC_RELAXED, __HIP_MEMORY_SCOPE_AGENT);

    // ---- out stores (plain, cached; off the critical path) ----
    if (lm < 8) {
      float* ob = out + (size_t)t * 65536 + dir * 512 + hb + (lm & ~1);
      if ((lm & 1) == 0) {
        *(float2*)(ob + (size_t)(b0 + 0) * 1024) = make_float2(hv[0], q0);
        *(float2*)(ob + (size_t)(b0 + 1) * 1024) = make_float2(hv[1], q1);
      } else {
        *(float2*)(ob + (size_t)(b0 + 2) * 1024) = make_float2(q2, hv[2]);
        *(float2*)(ob + (size_t)(b0 + 3) * 1024) = make_float2(q3, hv[3]);
      }
    }
  }

  // ---- final hT, cT ----
  if (lm < 8) {
    float* obase = out + 33554432 + dir * 65536;
#pragma unroll
    for (int r = 0; r < 4; ++r) {
      obase[(size_t)(b0 + r) * 512 + hb + u] = hlast[r];
      obase[32768 + (size_t)(b0 + r) * 512 + hb + u] = creg[r];
    }
  }
#undef LOADX
}

extern "C" void kernel_launch(void* const* d_in, const int* in_sizes, int n_in,
                              void* d_out, int out_size, void* d_ws, size_t ws_size,
                              hipStream_t stream) {
  (void)in_sizes; (void)n_in; (void)out_size; (void)ws_size;

  const float* X     = (const float*)d_in[0];
  const float* h0_f  = (const float*)d_in[1];
  const float* c0_f  = (const float*)d_in[2];
  const float* h0_b  = (const float*)d_in[3];
  const float* c0_b  = (const float*)d_in[4];
  const float* Wih_f = (const float*)d_in[5];
  const float* Whh_f = (const float*)d_in[6];
  const float* bih_f = (const float*)d_in[7];
  const float* bhh_f = (const float*)d_in[8];
  const float* Wih_b = (const float*)d_in[9];
  const float* Whh_b = (const float*)d_in[10];
  const float* bih_b = (const float*)d_in[11];
  const float* bhh_b = (const float*)d_in[12];
  float* out = (float*)d_out;

  unsigned short* xbf   = (unsigned short*)d_ws;                         // 33,554,432 B
  unsigned short* hbufs = (unsigned short*)((char*)d_ws + 33554432);     //    262,144 B
  int* flags            = (int*)((char*)d_ws + 33554432 + 262144);       //        512 B

  prep_x<<<16384, 256, 0, stream>>>((const float4*)X, (ushort4*)xbf);
  prep_init<<<256, 256, 0, stream>>>(h0_f, h0_b, hbufs, flags);

  lstm_coop<<<dim3(128), dim3(256), 0, stream>>>(
      xbf, hbufs, flags,
      Wih_f, Whh_f, bih_f, bhh_f, c0_f,
      Wih_b, Whh_b, bih_b, bhh_b, c0_b,
      out);
}

// Round 2
// 4030.824 us; speedup vs baseline: 2.3965x; 2.3965x over previous
//
#include <hip/hip_runtime.h>
#include <cstdint>
#include <cstddef>

#define T_ 512
#define B_ 64
#define I_ 512
#define H_ 512

typedef __attribute__((ext_vector_type(8))) short short8;
typedef __attribute__((ext_vector_type(4))) float f32x4;

#define MFMA(a, b, c) __builtin_amdgcn_mfma_f32_16x16x32_bf16((a), (b), (c), 0, 0, 0)

__device__ __forceinline__ unsigned short f2bf(float f) {
  union { float f; unsigned u; } v; v.f = f;
  unsigned r = v.u + 0x7fffu + ((v.u >> 16) & 1u);
  return (unsigned short)(r >> 16);
}

__device__ __forceinline__ float sigm(float x) { return 1.0f / (1.0f + __expf(-x)); }
__device__ __forceinline__ float tanh_fast(float x) {
  float e = __expf(2.0f * x);
  return 1.0f - 2.0f / (e + 1.0f);
}

__device__ __forceinline__ short8 loadWfrag(const float* __restrict__ p) {
  float4 a = ((const float4*)p)[0];
  float4 b = ((const float4*)p)[1];
  short8 r;
  r[0] = (short)f2bf(a.x); r[1] = (short)f2bf(a.y);
  r[2] = (short)f2bf(a.z); r[3] = (short)f2bf(a.w);
  r[4] = (short)f2bf(b.x); r[5] = (short)f2bf(b.y);
  r[6] = (short)f2bf(b.z); r[7] = (short)f2bf(b.w);
  return r;
}

// ---- prep: convert X (T,B,I) fp32 -> bf16 in ws. 16384x256 threads, 1 float4 each.
__global__ void prep_x(const float4* __restrict__ x, ushort4* __restrict__ xb) {
  int i = blockIdx.x * 256 + threadIdx.x;
  float4 v = x[i];
  ushort4 o;
  o.x = f2bf(v.x); o.y = f2bf(v.y); o.z = f2bf(v.z); o.w = f2bf(v.w);
  xb[i] = o;
}

// ---- prep: h0 -> bf16 parity-0 buffers, zero padded flags. 256x256 threads.
__global__ void prep_init(const float* __restrict__ h0f, const float* __restrict__ h0b,
                          unsigned short* __restrict__ hbufs, int* __restrict__ flags) {
  int i = blockIdx.x * 256 + threadIdx.x;
  if (i < 32768) {
    hbufs[i] = f2bf(h0f[i]);                    // dir0, parity0
  } else {
    int j = i - 32768;
    hbufs[2 * 32768 + j] = f2bf(h0b[j]);        // dir1, parity0
  }
  if (i < 8192) flags[i] = 0;                   // 512 flags x 16-int (64B) padding
}

// ---- persistent bidirectional LSTM. grid=128 (64 WGs/dir), block=256.
// Zero LDS, zero __syncthreads. Per-wave dataflow with DIAGONAL flags:
//   consumer wave w reads h rows [16w,16w+16) == output of wave w of every
//   producer WG, so flags are per-(dir,jw,wave), one per 64B line.
// Step: x-MFMAs (prefetched, pre-poll) -> poll 64 diag flags (padded lines)
//   -> sc1 h loads direct to A-fragments -> h MFMAs -> shfl epilogue ->
//   sc1 h stores -> fence -> x prefetch (16 loads) -> s_waitcnt vmcnt(16)
//   (drains stores only; prefetch stays in flight) -> post own flag (plain
//   relaxed store, single writer) -> out stores (off critical path).
// Buffer-parity safety: wave passing poll-for-s proves all readers of
// h^(s-1) slice (waves (jw',w) at step s-1) retired their reads (reads
// precede their step-(s-1) store drain and flag post). Posts are monotonic,
// 128 blocks @ (256,1) are capacity-co-resident on 256 CUs: no deadlock.
__global__ __launch_bounds__(256, 1) void lstm_coop(
    const unsigned short* __restrict__ xbf,
    unsigned short* __restrict__ hbufs,
    int* __restrict__ flags,
    const float* __restrict__ Wih_f, const float* __restrict__ Whh_f,
    const float* __restrict__ bih_f, const float* __restrict__ bhh_f,
    const float* __restrict__ c0_f,
    const float* __restrict__ Wih_b, const float* __restrict__ Whh_b,
    const float* __restrict__ bih_b, const float* __restrict__ bhh_b,
    const float* __restrict__ c0_b,
    float* __restrict__ out) {
  const int tid = threadIdx.x;
  const int wave = tid >> 6;
  const int lane = tid & 63;
  const int quad = lane >> 4;
  const int lm = lane & 15;

  const int wg = blockIdx.x;
  const int dir = wg >> 6;       // 0 = forward, 1 = backward
  const int jw = wg & 63;        // hidden-slice index
  const int hb = jw * 8;         // first hidden unit owned

  const float* Wih = dir ? Wih_b : Wih_f;
  const float* Whh = dir ? Whh_b : Whh_f;
  const float* bih = dir ? bih_b : bih_f;
  const float* bhh = dir ? bhh_b : bhh_f;
  const float* c0  = dir ? c0_b  : c0_f;

  // ---- weight fragments: 32 gate rows x K=512, both matrices, in registers ----
  short8 wx[2][16], wh[2][16];
#pragma unroll
  for (int nt = 0; nt < 2; ++nt) {
    int nl = nt * 16 + lm;                         // local gate-row 0..31
    int row = (nl >> 3) * 512 + hb + (nl & 7);     // global row in (4H, 512)
#pragma unroll
    for (int kk = 0; kk < 16; ++kk) {
      int k = kk * 32 + quad * 8;
      wx[nt][kk] = loadWfrag(Wih + (size_t)row * 512 + k);
      wh[nt][kk] = loadWfrag(Whh + (size_t)row * 512 + k);
    }
  }

  // ---- epilogue ownership: lane (quad,lm) -> unit u=lm&7, batches b0..b0+3.
  // Lanes lm and lm+8 duplicate c/h math (deterministic identical); lm<8 stores.
  const int u = lm & 15 & 7;
  float bsum[4];
#pragma unroll
  for (int g = 0; g < 4; ++g)
    bsum[g] = bih[g * 512 + hb + u] + bhh[g * 512 + hb + u];

  const int b0 = wave * 16 + quad * 4;
  float creg[4], hlast[4];
#pragma unroll
  for (int r = 0; r < 4; ++r) {
    creg[r] = c0[(size_t)(b0 + r) * 512 + hb + u];
    hlast[r] = 0.f;
  }

  unsigned short* hbuf = hbufs + (size_t)(dir * 2) * 32768;  // parity buffers, my dir

  // flag addressing: flag(dir, j, w) at int offset (dir*64 + j)*64 + w*16 (64B apart)
  int* mypost = flags + ((size_t)(dir * 64 + jw) * 64 + wave * 16);
  const int* mypoll = flags + ((size_t)(dir * 64 + lane) * 64 + wave * 16);

  const int arow = wave * 16 + lm;                // batch row this lane feeds to MFMA A
  const unsigned short* xrow = xbf + (size_t)arow * 512 + quad * 8;

  short8 xf[16];                                  // x A-fragments (prefetched)
#define LOADX(tt)                                                         \
  {                                                                       \
    const short8* xs = (const short8*)(xrow + (size_t)(tt) * 32768);      \
    _Pragma("unroll")                                                     \
    for (int kk = 0; kk < 16; ++kk) xf[kk] = xs[kk * 4];                  \
  }

  LOADX(dir ? 511 : 0);

  for (int s = 0; s < 512; ++s) {
    const int t = dir ? (511 - s) : s;

    // ---- x MFMAs: no h dependency, run before/while the flag is pending ----
    f32x4 acc0 = {0.f, 0.f, 0.f, 0.f};
    f32x4 acc1 = {0.f, 0.f, 0.f, 0.f};
#pragma unroll
    for (int kk = 0; kk < 16; ++kk) {
      acc0 = MFMA(xf[kk], wx[0][kk], acc0);
      acc1 = MFMA(xf[kk], wx[1][kk], acc1);
    }

    // ---- diag poll: lane i waits for producer wave (i, wave) to finish s-1 ----
    while (__hip_atomic_load(mypoll, __ATOMIC_RELAXED, __HIP_MEMORY_SCOPE_AGENT) < s)
      __builtin_amdgcn_s_sleep(1);
    asm volatile("" ::: "memory");  // keep h loads below the poll

    // ---- h A-fragment loads (sc1: bypass stale L2), direct to regs ----
    const unsigned long long* hsrc =
        (const unsigned long long*)(hbuf + (size_t)(s & 1) * 32768) +
        (size_t)arow * 128 + quad * 2;
    unsigned long long hq[32];
#pragma unroll
    for (int kk = 0; kk < 16; ++kk) {
      hq[2 * kk]     = __hip_atomic_load(hsrc + kk * 8,     __ATOMIC_RELAXED, __HIP_MEMORY_SCOPE_AGENT);
      hq[2 * kk + 1] = __hip_atomic_load(hsrc + kk * 8 + 1, __ATOMIC_RELAXED, __HIP_MEMORY_SCOPE_AGENT);
    }

    // ---- h MFMAs (in-order vmcnt waits pipeline against hq loads) ----
#pragma unroll
    for (int kk = 0; kk < 16; ++kk) {
      ulonglong2 t2; t2.x = hq[2 * kk]; t2.y = hq[2 * kk + 1];
      short8 a = __builtin_bit_cast(short8, t2);
      acc0 = MFMA(a, wh[0][kk], acc0);
      acc1 = MFMA(a, wh[1][kk], acc1);
    }

    // ---- gate exchange within lane pair (lm ^ 8): D col=lane&15 holds
    // i/f (acc0) and g/o (acc1); partner lane has the other half ----
    float hv[4];
#pragma unroll
    for (int r = 0; r < 4; ++r) {
      float p0 = __shfl_xor(acc0[r], 8, 64);
      float p1 = __shfl_xor(acc1[r], 8, 64);
      float gi  = (lm < 8 ? acc0[r] : p0) + bsum[0];
      float gfr = (lm < 8 ? p0 : acc0[r]) + bsum[1];
      float gg  = (lm < 8 ? acc1[r] : p1) + bsum[2];
      float go  = (lm < 8 ? p1 : acc1[r]) + bsum[3];
      float cn = sigm(gfr) * creg[r] + sigm(gi) * tanh_fast(gg);
      creg[r] = cn;
      hv[r] = sigm(go) * tanh_fast(cn);
      hlast[r] = hv[r];
    }
    // unit-pair packing for 4B stores: partner lane (lm^1) has unit u^1
    float q0 = __shfl_xor(hv[0], 1, 64), q1 = __shfl_xor(hv[1], 1, 64);
    float q2 = __shfl_xor(hv[2], 1, 64), q3 = __shfl_xor(hv[3], 1, 64);

    // ---- h slice stores (sc1 write-through), 2 x 4B per low lane ----
    unsigned short* hdst = hbuf + (size_t)((s + 1) & 1) * 32768;
    if (lm < 8) {
      unsigned short* hp = hdst + hb + (lm & ~1);
      if ((lm & 1) == 0) {
        unsigned pa = (unsigned)f2bf(hv[0]) | ((unsigned)f2bf(q0) << 16);
        unsigned pb = (unsigned)f2bf(hv[1]) | ((unsigned)f2bf(q1) << 16);
        __hip_atomic_store((unsigned*)(hp + (size_t)(b0 + 0) * 512), pa,
                           __ATOMIC_RELAXED, __HIP_MEMORY_SCOPE_AGENT);
        __hip_atomic_store((unsigned*)(hp + (size_t)(b0 + 1) * 512), pb,
                           __ATOMIC_RELAXED, __HIP_MEMORY_SCOPE_AGENT);
      } else {
        unsigned pa = (unsigned)f2bf(q2) | ((unsigned)f2bf(hv[2]) << 16);
        unsigned pb = (unsigned)f2bf(q3) | ((unsigned)f2bf(hv[3]) << 16);
        __hip_atomic_store((unsigned*)(hp + (size_t)(b0 + 2) * 512), pa,
                           __ATOMIC_RELAXED, __HIP_MEMORY_SCOPE_AGENT);
        __hip_atomic_store((unsigned*)(hp + (size_t)(b0 + 3) * 512), pb,
                           __ATOMIC_RELAXED, __HIP_MEMORY_SCOPE_AGENT);
      }
    }
    // pin: all h stores issue BEFORE the prefetch loads (in-order vmcnt retire)
    asm volatile("" ::: "memory");

    // ---- prefetch x for next step: 16 loads, stay in flight across the post ----
    {
      int sn = s + 1 < 512 ? s + 1 : 511;
      LOADX(dir ? (511 - sn) : sn);
    }
    // drain the h stores only (16 newest = prefetch loads remain outstanding)
    asm volatile("s_waitcnt vmcnt(16)" ::: "memory");
    if (lane == 0)
      __hip_atomic_store(mypost, s + 1, __ATOMIC_RELAXED, __HIP_MEMORY_SCOPE_AGENT);

    // ---- out stores (plain, cached; fully off the critical path) ----
    if (lm < 8) {
      float* ob = out + (size_t)t * 65536 + dir * 512 + hb + (lm & ~1);
      if ((lm & 1) == 0) {
        *(float2*)(ob + (size_t)(b0 + 0) * 1024) = make_float2(hv[0], q0);
        *(float2*)(ob + (size_t)(b0 + 1) * 1024) = make_float2(hv[1], q1);
      } else {
        *(float2*)(ob + (size_t)(b0 + 2) * 1024) = make_float2(q2, hv[2]);
        *(float2*)(ob + (size_t)(b0 + 3) * 1024) = make_float2(q3, hv[3]);
      }
    }
  }

  // ---- final hT, cT ----
  if (lm < 8) {
    float* obase = out + 33554432 + dir * 65536;
#pragma unroll
    for (int r = 0; r < 4; ++r) {
      obase[(size_t)(b0 + r) * 512 + hb + u] = hlast[r];
      obase[32768 + (size_t)(b0 + r) * 512 + hb + u] = creg[r];
    }
  }
#undef LOADX
}

extern "C" void kernel_launch(void* const* d_in, const int* in_sizes, int n_in,
                              void* d_out, int out_size, void* d_ws, size_t ws_size,
                              hipStream_t stream) {
  (void)in_sizes; (void)n_in; (void)out_size; (void)ws_size;

  const float* X     = (const float*)d_in[0];
  const float* h0_f  = (const float*)d_in[1];
  const float* c0_f  = (const float*)d_in[2];
  const float* h0_b  = (const float*)d_in[3];
  const float* c0_b  = (const float*)d_in[4];
  const float* Wih_f = (const float*)d_in[5];
  const float* Whh_f = (const float*)d_in[6];
  const float* bih_f = (const float*)d_in[7];
  const float* bhh_f = (const float*)d_in[8];
  const float* Wih_b = (const float*)d_in[9];
  const float* Whh_b = (const float*)d_in[10];
  const float* bih_b = (const float*)d_in[11];
  const float* bhh_b = (const float*)d_in[12];
  float* out = (float*)d_out;

  unsigned short* xbf   = (unsigned short*)d_ws;                         // 33,554,432 B
  unsigned short* hbufs = (unsigned short*)((char*)d_ws + 33554432);     //    262,144 B
  int* flags            = (int*)((char*)d_ws + 33554432 + 262144);       //     32,768 B (512 flags, 64B-padded)

  prep_x<<<16384, 256, 0, stream>>>((const float4*)X, (ushort4*)xbf);
  prep_init<<<256, 256, 0, stream>>>(h0_f, h0_b, hbufs, flags);

  lstm_coop<<<dim3(128), dim3(256), 0, stream>>>(
      xbf, hbufs, flags,
      Wih_f, Whh_f, bih_f, bhh_f, c0_f,
      Wih_b, Whh_b, bih_b, bhh_b, c0_b,
      out);
}